// Round 3
// baseline (227.799 us; speedup 1.0000x reference)
//
#include <hip/hip_runtime.h>
#include <utility>

using u16 = unsigned short;
using u32 = unsigned int;

typedef float  f32x4  __attribute__((ext_vector_type(4)));
typedef __bf16 bf16x8 __attribute__((ext_vector_type(8)));

#define DI __device__ __forceinline__

// ------------------------------------------------------------------
// Monomial basis under the +4 rotation group (for 16x16x32 MFMA).
// Monomials over x[0..15]: cubic (816), quadratic (136), linear (16).
// Group action: rotation by +4q mod 16 (q=0..3).  Cubic orbits all size
// 4 -> 204 reps; quad: 32 size-4 orbits + 8 size-2 ({a,a+8}) -> 36 reps
// (8 dup slots stay null); linear -> 4 reps.  204+36+4 = 244, padded to
// 248 = 31 chunks * 8.
// Feature slot f = chunk*32 + q*8 + j  <->  rep r = chunk*8 + j,
// monomial = rot_{4q}(rep[r]).  Lane quad q = lane>>4 holds x rotated by
// 4q at the address level, so all lanes run identical compile-time code.
// ------------------------------------------------------------------
struct RepT { unsigned char a, b, c, t; };   // t: 3=cubic 2=quad 1=linear 0=null
struct Tables4 {
  RepT rep[248];        // compile-time rep list for feature templates
  RepT slotmono[992];   // per feature-slot: SORTED monomial (prep gather); t=0 if null/dup
  int n3, n2, n1;
};

constexpr int csort3key(int w, int x, int i) {
  int a = w, b = x, c = i, t = 0;
  if (a > b) { t = a; a = b; b = t; }
  if (b > c) { t = b; b = c; c = t; }
  if (a > b) { t = a; a = b; b = t; }
  return (a << 8) | (b << 4) | c;
}

constexpr Tables4 build_tables4() {
  Tables4 T = {};
  bool used3[4096] = {};
  bool used2[256] = {};
  int nr = 0;
  // cubic multisets a<=b<=c, canonical = lex-min over the 4 rotations
  for (int a = 0; a < 16; a++) for (int b = a; b < 16; b++) for (int c = b; c < 16; c++) {
    const int key = (a << 8) | (b << 4) | c;
    bool canon = true;
    for (int q = 1; q < 4; q++)
      if (csort3key((a + 4 * q) & 15, (b + 4 * q) & 15, (c + 4 * q) & 15) < key) canon = false;
    if (!canon) continue;
    for (int q = 0; q < 4; q++) {
      const int kk = csort3key((a + 4 * q) & 15, (b + 4 * q) & 15, (c + 4 * q) & 15);
      if (!used3[kk]) {
        used3[kk] = true;
        const int f = (nr >> 3) * 32 + q * 8 + (nr & 7);
        T.slotmono[f].a = (unsigned char)(kk >> 8);
        T.slotmono[f].b = (unsigned char)((kk >> 4) & 15);
        T.slotmono[f].c = (unsigned char)(kk & 15);
        T.slotmono[f].t = 3;
      }
    }
    T.rep[nr].a = (unsigned char)a; T.rep[nr].b = (unsigned char)b;
    T.rep[nr].c = (unsigned char)c; T.rep[nr].t = 3; nr++;
  }
  T.n3 = nr;
  // quadratic multisets a<=b
  for (int a = 0; a < 16; a++) for (int b = a; b < 16; b++) {
    const int key = (a << 4) | b;
    bool canon = true;
    for (int q = 1; q < 4; q++) {
      int aa = (a + 4 * q) & 15, bb = (b + 4 * q) & 15;
      if (aa > bb) { int t = aa; aa = bb; bb = t; }
      if (((aa << 4) | bb) < key) canon = false;
    }
    if (!canon) continue;
    for (int q = 0; q < 4; q++) {
      int aa = (a + 4 * q) & 15, bb = (b + 4 * q) & 15;
      if (aa > bb) { int t = aa; aa = bb; bb = t; }
      const int kk = (aa << 4) | bb;
      if (!used2[kk]) {
        used2[kk] = true;
        const int f = (nr >> 3) * 32 + q * 8 + (nr & 7);
        T.slotmono[f].a = (unsigned char)(kk >> 4);
        T.slotmono[f].b = (unsigned char)(kk & 15);
        T.slotmono[f].c = 0;
        T.slotmono[f].t = 2;
      }
    }
    T.rep[nr].a = (unsigned char)a; T.rep[nr].b = (unsigned char)b;
    T.rep[nr].c = 0; T.rep[nr].t = 2; nr++;
  }
  T.n2 = nr;
  // linear: reps 0..3, orbit {a, a+4, a+8, a+12}
  for (int a = 0; a < 4; a++) {
    for (int q = 0; q < 4; q++) {
      const int f = (nr >> 3) * 32 + q * 8 + (nr & 7);
      T.slotmono[f].a = (unsigned char)((a + 4 * q) & 15);
      T.slotmono[f].b = 0; T.slotmono[f].c = 0; T.slotmono[f].t = 1;
    }
    T.rep[nr].a = (unsigned char)a; T.rep[nr].b = 0; T.rep[nr].c = 0;
    T.rep[nr].t = 1; nr++;
  }
  T.n1 = nr;
  for (; nr < 248; nr++) { T.rep[nr].a = 0; T.rep[nr].b = 0; T.rep[nr].c = 0; T.rep[nr].t = 0; }
  return T;
}

constexpr Tables4 TT4 = build_tables4();
static_assert(TT4.n3 == 204, "cubic rep count");
static_assert(TT4.n2 == 240, "quad rep count");
static_assert(TT4.n1 == 244, "linear rep count");

__device__ const Tables4 g_T4 = build_tables4();   // runtime copy for prep kernel

// dims
#define BN 5888
#define CN 128
#define EN 10
#define NCHUNK 31          // 248 reps / 8; K = 992
#define NPATH 32           // 23 + 4 + 1 padded
#define H0 16              // chunks in half 0
#define H1 15              // chunks in half 1

DI u16 f2bf(float f) { union { __bf16 h; u16 s; } u; u.h = (__bf16)f; return u.s; }
DI float bf2f(u16 v) { union { u32 u; float f; } w; w.u = ((u32)v) << 16; return w.f; }

// ------------------------------------------------------------------
// prep kernel: ONE dispatch, no memset, no atomics.  One thread per
// packed-fragment u16: gathers its monomial's <=6 distinct U-index
// permutations, sums, converts to bf16, writes coalesced.
// Fragment layout (matches main's staging copy exactly):
// uint4 idx = cp*64 + l; cp = chunk*2 + P; lane l: path = P*16 + (l&15),
// q = l>>4; u16 j in [0,8): feature slot = chunk*32 + q*8 + j.
// ------------------------------------------------------------------
#define PREP_THREADS (NCHUNK * 2 * 64 * 8)     // 31744 u16 = 62 KB

__global__ void prep_kernel(const float* __restrict__ U3, const float* __restrict__ U2,
                            const float* __restrict__ U1, u16* __restrict__ Sfrag16) {
  const int tid = blockIdx.x * 256 + threadIdx.x;
  if (tid >= PREP_THREADS) return;
  const int j = tid & 7, l = (tid >> 3) & 63, cp = tid >> 9;
  const int chunk = cp >> 1, P = cp & 1;
  const int path = P * 16 + (l & 15), q = l >> 4;
  const RepT m = g_T4.slotmono[chunk * 32 + q * 8 + j];
  float v = 0.f;
  if (m.t == 3 && path < 23) {
    const int a = m.a, b = m.b, d = m.c;
    v = U3[((a * 16 + b) * 16 + d) * 23 + path];
    if (a == b && b == d) {
      // single distinct permutation
    } else if (a == b) {            // (a,a,d): +ada, +daa
      v += U3[((a * 16 + d) * 16 + a) * 23 + path]
         + U3[((d * 16 + a) * 16 + a) * 23 + path];
    } else if (b == d) {            // (a,b,b): +bab, +bba
      v += U3[((b * 16 + a) * 16 + b) * 23 + path]
         + U3[((b * 16 + b) * 16 + a) * 23 + path];
    } else {                        // all distinct: 6 perms
      v += U3[((a * 16 + d) * 16 + b) * 23 + path]
         + U3[((b * 16 + a) * 16 + d) * 23 + path]
         + U3[((b * 16 + d) * 16 + a) * 23 + path]
         + U3[((d * 16 + a) * 16 + b) * 23 + path]
         + U3[((d * 16 + b) * 16 + a) * 23 + path];
    }
  } else if (m.t == 2 && path >= 23 && path < 27) {
    const int k = path - 23, a = m.a, b = m.b;
    v = U2[(a * 16 + b) * 4 + k];
    if (a != b) v += U2[(b * 16 + a) * 4 + k];
  } else if (m.t == 1 && path == 27) {
    v = U1[m.a];
  }
  Sfrag16[tid] = f2bf(v);
}

// ------------------------------------------------------------------
// main kernel (16x16x32 MFMA).  Journal of hard-won constraints:
//  - VGPR 44-48 spill-free; NEVER pass a min-waves launch_bounds arg
//    (round 0 of this session: clamped to 32 VGPR -> 430 MB/dispatch
//    scratch traffic).
//  - NO sched_barrier (prior round 10: 8x regression).
//  - w-reads must be block-coalesced once (prior round 5: per-lane
//    w-loads -> 990 MB L2 fetch).
//  - Round 1 evidence: MfmaUtil*dur ~= 20 us = MFMA floor; VALUBusy 49%
//    at Occupancy 38.7% (ONE 16-wave block/CU resident; 78 KB blocks
//    co-schedule only marginally).  VALU-issue-bound at low occupancy.
// THIS ROUND: K-split.  31 chunks -> halves of 16+15.  Each 512-thread
// block stages only its half of S (32 KB) + 28-row wbl (7 KB) = 39.9 KB
// -> 4 blocks/CU = 32 waves/CU (hardware wave cap), robust to losing a
// slot (3 blocks = 24 waves still > today).  Two blocks per node
// (interleaved blockIdx for locality) combine via atomicAdd into a
// memset-zeroed out.  Padded paths 28..31 have identically-zero S rows
// -> dropped from wbl (q<3 guard on the upper path-tile).
// ------------------------------------------------------------------
template<int R>
DI float featf(const float* xr) {
  constexpr RepT rp = TT4.rep[R];
  if constexpr (rp.t == 3) return xr[rp.a] * xr[rp.b] * xr[rp.c];
  else if constexpr (rp.t == 2) return xr[rp.a] * xr[rp.b];
  else if constexpr (rp.t == 1) return xr[rp.a];
  else return 0.f;
}

template<int C>
DI bf16x8 make_B(const float* xr) {
  bf16x8 r;
  r[0] = (__bf16)featf<C * 8 + 0>(xr);
  r[1] = (__bf16)featf<C * 8 + 1>(xr);
  r[2] = (__bf16)featf<C * 8 + 2>(xr);
  r[3] = (__bf16)featf<C * 8 + 3>(xr);
  r[4] = (__bf16)featf<C * 8 + 4>(xr);
  r[5] = (__bf16)featf<C * 8 + 5>(xr);
  r[6] = (__bf16)featf<C * 8 + 6>(xr);
  r[7] = (__bf16)featf<C * 8 + 7>(xr);
  return r;
}

// A: path/k fragment from LDS (2 path-tiles); B: 8 features of this pair.
// B built before the A-loads to keep A's live range ds_read -> MFMA.
// CB = first chunk staged in this block's sfrag (LDS rebase).
template<int C, int CB>
DI void chunk_step(const uint4* sfl, const float* xr, f32x4& a0, f32x4& a1) {
  const bf16x8 B = make_B<C>(xr);
  const bf16x8 A0 = *reinterpret_cast<const bf16x8*>(sfl + ((C - CB) * 2 + 0) * 64);
  const bf16x8 A1 = *reinterpret_cast<const bf16x8*>(sfl + ((C - CB) * 2 + 1) * 64);
  a0 = __builtin_amdgcn_mfma_f32_16x16x32_bf16(A0, B, a0, 0, 0, 0);
  a1 = __builtin_amdgcn_mfma_f32_16x16x32_bf16(A1, B, a1, 0, 0, 0);
}

template<int CB, int... Cs>
DI void run_chunks(std::integer_sequence<int, Cs...>, const uint4* sfl,
                   const float* xr, f32x4& a0, f32x4& a1) {
  (chunk_step<CB + Cs, CB>(sfl, xr, a0, a1), ...);
}

// xr[v] = x[pair][(v + 4q) & 15] via float4-group rotation at address level
DI void load_xr(const float* __restrict__ x, int pair, int q, float* xr) {
  const float* base = x + pair * 16;
#pragma unroll
  for (int u = 0; u < 4; u++) {
    const int g = (u + q) & 3;
    const float4 v = *(const float4*)(base + g * 4);
    xr[u * 4 + 0] = v.x;
    xr[u * 4 + 1] = v.y;
    xr[u * 4 + 2] = v.z;
    xr[u * 4 + 3] = v.w;
  }
}

// 512-thread blocks, one node-half each.  LDS = 32 KB sfrag (16-chunk
// worst case) + 7 KB wbl = 39936 B -> 4 blocks/CU (159.7 KB) = 32
// waves/CU.  NO min-waves arg (round 0 lesson).
__global__ __launch_bounds__(512) void main_kernel(
    const float* __restrict__ x, const float* __restrict__ y,
    const float* __restrict__ w3, const float* __restrict__ w2, const float* __restrict__ w1,
    const uint4* __restrict__ Sfrag, float* __restrict__ out)
{
  __shared__ uint4 sfrag[H0 * 2 * 64];         // 32 KB (half1 uses 30 KB of it)
  __shared__ u16  wbl[28 * 128];               // 7 KB: WB[path][c] bf16, real paths only
  const int tid = threadIdx.x;
  const int half = blockIdx.x & 1;             // interleaved: node's halves adjacent
  const int node = blockIdx.x >> 1;

  // stage this half's S fragments: straight uint4 copy
  const int nfrag = half ? (H1 * 2 * 64) : (H0 * 2 * 64);
  const uint4* srcS = Sfrag + (half ? (H0 * 2 * 64) : 0);
  for (int idx = tid; idx < nfrag; idx += 512) sfrag[idx] = srcS[idx];

  // per-node WB = y[b] @ concat(w3,w2,w1): thread t -> p = t>>4,
  // c-octet = (t&15)*8 : exactly 512.  Coalesced w-reads ONCE per block
  // (prior round 5 lesson).  Runs in both halves (cheap, ~150 instr).
  {
    const int p  = tid >> 4;
    const int c0 = (tid & 15) * 8;
    float yv[EN];
#pragma unroll
    for (int e = 0; e < EN; e++) yv[e] = y[node * EN + e];
    float acc[8];
#pragma unroll
    for (int m = 0; m < 8; m++) acc[m] = 0.f;
    const float* wsrc = nullptr; int stride = 0;
    if (p < 23)       { wsrc = w3 + p * 128;        stride = 23 * 128; }
    else if (p < 27)  { wsrc = w2 + (p - 23) * 128; stride = 4 * 128; }
    else if (p == 27) { wsrc = w1;                  stride = 128; }
    if (wsrc) {
      for (int e = 0; e < EN; e++) {
        const float* src = wsrc + e * stride + c0;
        const float4 v0 = *(const float4*)(src);
        const float4 v1 = *(const float4*)(src + 4);
        acc[0] += yv[e] * v0.x; acc[1] += yv[e] * v0.y;
        acc[2] += yv[e] * v0.z; acc[3] += yv[e] * v0.w;
        acc[4] += yv[e] * v1.x; acc[5] += yv[e] * v1.y;
        acc[6] += yv[e] * v1.z; acc[7] += yv[e] * v1.w;
      }
    }
    if (p < 28) {
#pragma unroll
      for (int m = 0; m < 8; m++) wbl[p * 128 + c0 + m] = f2bf(acc[m]);
    }
  }
  __syncthreads();

  // wave handles 16 pairs (1 pair-tile); block = 128 pairs = 1 node
  const int wn = tid >> 6, lane = tid & 63;
  const int q = lane >> 4, n = lane & 15;
  const int pair0 = node * 128 + wn * 16 + n;

  float xr[16];
  load_xr(x, pair0, q, xr);

  const uint4* sfl = sfrag + lane;
  f32x4 a0 = {0.f, 0.f, 0.f, 0.f};
  f32x4 a1 = a0;
  if (half == 0)
    run_chunks<0>(std::make_integer_sequence<int, H0>{}, sfl, xr, a0, a1);
  else
    run_chunks<H0>(std::make_integer_sequence<int, H1>{}, sfl, xr, a0, a1);

  // epilogue: partial out[pair] = sum_p D[p][pair] * WB[p][c], quad-reduce,
  // atomicAdd combines the two K-halves (out pre-zeroed by memset).
  // D layout (16x16x32): col = lane&15 = pair, row = q*4+rg = path.
  // Upper path-tile rows 16+q*4+rg >= 28 occur exactly at q==3 and have
  // identically-zero D (padded S rows) -> skip, keeps wbl at 28 rows.
  const int cc = wn * 16 + n;              // channel = pair0 % 128
  float p0 = 0.f;
#pragma unroll
  for (int rg = 0; rg < 4; rg++) p0 += a0[rg] * bf2f(wbl[(q * 4 + rg) * 128 + cc]);
  if (q < 3) {
#pragma unroll
    for (int rg = 0; rg < 4; rg++) p0 += a1[rg] * bf2f(wbl[(16 + q * 4 + rg) * 128 + cc]);
  }
  p0 += __shfl_xor(p0, 16);
  p0 += __shfl_xor(p0, 32);
  if (q == 0) atomicAdd(&out[pair0], p0);
}

// ------------------------------------------------------------------
extern "C" void kernel_launch(void* const* d_in, const int* in_sizes, int n_in,
                              void* d_out, int out_size, void* d_ws, size_t ws_size,
                              hipStream_t stream) {
  const float* x  = (const float*)d_in[0];
  const float* y  = (const float*)d_in[1];
  const float* U3 = (const float*)d_in[2];
  const float* U2 = (const float*)d_in[3];
  const float* U1 = (const float*)d_in[4];
  const float* w3 = (const float*)d_in[5];
  const float* w2 = (const float*)d_in[6];
  const float* w1 = (const float*)d_in[7];
  u16*   Sfrag16 = (u16*)d_ws;
  float* out     = (float*)d_out;

  hipMemsetAsync(out, 0, out_size, stream);    // atomic accumulation target
  hipLaunchKernelGGL(prep_kernel, dim3((PREP_THREADS + 255) / 256), dim3(256), 0, stream,
                     U3, U2, U1, Sfrag16);
  hipLaunchKernelGGL(main_kernel, dim3(BN * 2), dim3(512), 0, stream,
                     x, y, w3, w2, w1, (const uint4*)d_ws, out);
}

// Round 4
// 179.085 us; speedup vs baseline: 1.2720x; 1.2720x over previous
//
#include <hip/hip_runtime.h>
#include <utility>

using u16 = unsigned short;
using u32 = unsigned int;

typedef float  f32x4   __attribute__((ext_vector_type(4)));
typedef float  f32x16  __attribute__((ext_vector_type(16)));
typedef __bf16 bf16x8  __attribute__((ext_vector_type(8)));

#define DI __device__ __forceinline__

// ------------------------------------------------------------------
// Monomial basis under the +8 rotation group (for 32x32x16 MFMA).
// Monomials over x[0..15]: cubic (816), quadratic (136), linear (16).
// Group action: rotation by +8q mod 16 (q=0..1).  Cubic orbits all size
// 2 (parity: 3*8=24 != 0 mod 16) -> 408 reps; quad: 8 fixed orbits
// {a,a+8} + 64 size-2 -> 72 reps (8 dup slots stay null); linear -> 8
// reps.  408+72+8 = 488 = 61 chunks * 8 exactly (no padding).
// Feature slot f = chunk*16 + q*8 + j  <->  rep r = chunk*8 + j,
// monomial = rot_{8q}(rep[r]).  Lane half q = lane>>5 holds x rotated by
// 8q at the address level, so all lanes run identical compile-time code.
// ------------------------------------------------------------------
struct RepT { unsigned char a, b, c, t; };   // t: 3=cubic 2=quad 1=linear 0=null
struct Tables8 {
  RepT rep[488];        // compile-time rep list for feature templates
  RepT slotmono[976];   // per feature-slot: SORTED monomial (prep gather); t=0 if dup
  int n3, n2, n1;
};

constexpr int csort3key(int w, int x, int i) {
  int a = w, b = x, c = i, t = 0;
  if (a > b) { t = a; a = b; b = t; }
  if (b > c) { t = b; b = c; c = t; }
  if (a > b) { t = a; a = b; b = t; }
  return (a << 8) | (b << 4) | c;
}
constexpr int csort2key(int a, int b) { return a <= b ? ((a << 4) | b) : ((b << 4) | a); }

constexpr Tables8 build_tables8() {
  Tables8 T = {};
  bool used3[4096] = {};
  bool used2[256] = {};
  int nr = 0;
  // cubic multisets a<=b<=c, canonical = lex-min of {self, +8 rotation}
  for (int a = 0; a < 16; a++) for (int b = a; b < 16; b++) for (int c = b; c < 16; c++) {
    const int key  = (a << 8) | (b << 4) | c;
    const int rkey = csort3key((a + 8) & 15, (b + 8) & 15, (c + 8) & 15);
    if (rkey < key) continue;                 // partner is the canonical one
    for (int q = 0; q < 2; q++) {
      const int kk = q ? rkey : key;
      if (!used3[kk]) {
        used3[kk] = true;
        const int f = (nr >> 3) * 16 + q * 8 + (nr & 7);
        T.slotmono[f].a = (unsigned char)(kk >> 8);
        T.slotmono[f].b = (unsigned char)((kk >> 4) & 15);
        T.slotmono[f].c = (unsigned char)(kk & 15);
        T.slotmono[f].t = 3;
      }
    }
    T.rep[nr].a = (unsigned char)a; T.rep[nr].b = (unsigned char)b;
    T.rep[nr].c = (unsigned char)c; T.rep[nr].t = 3; nr++;
  }
  T.n3 = nr;
  // quadratic multisets a<=b
  for (int a = 0; a < 16; a++) for (int b = a; b < 16; b++) {
    const int key  = (a << 4) | b;
    const int rkey = csort2key((a + 8) & 15, (b + 8) & 15);
    if (rkey < key) continue;
    for (int q = 0; q < 2; q++) {
      const int kk = q ? rkey : key;
      if (!used2[kk]) {                      // fixed orbits: q=1 slot stays null
        used2[kk] = true;
        const int f = (nr >> 3) * 16 + q * 8 + (nr & 7);
        T.slotmono[f].a = (unsigned char)(kk >> 4);
        T.slotmono[f].b = (unsigned char)(kk & 15);
        T.slotmono[f].c = 0;
        T.slotmono[f].t = 2;
      }
    }
    T.rep[nr].a = (unsigned char)a; T.rep[nr].b = (unsigned char)b;
    T.rep[nr].c = 0; T.rep[nr].t = 2; nr++;
  }
  T.n2 = nr;
  // linear: reps 0..7, orbit {a, a+8}
  for (int a = 0; a < 8; a++) {
    for (int q = 0; q < 2; q++) {
      const int f = (nr >> 3) * 16 + q * 8 + (nr & 7);
      T.slotmono[f].a = (unsigned char)((a + 8 * q) & 15);
      T.slotmono[f].b = 0; T.slotmono[f].c = 0; T.slotmono[f].t = 1;
    }
    T.rep[nr].a = (unsigned char)a; T.rep[nr].b = 0; T.rep[nr].c = 0;
    T.rep[nr].t = 1; nr++;
  }
  T.n1 = nr;
  return T;
}

constexpr Tables8 TT8 = build_tables8();
static_assert(TT8.n3 == 408, "cubic rep count");
static_assert(TT8.n2 == 480, "quad rep count");
static_assert(TT8.n1 == 488, "linear rep count");   // 61 chunks * 8, exact

__device__ const Tables8 g_T8 = build_tables8();   // runtime copy for prep kernel

// dims
#define BN 5888
#define CN 128
#define EN 10
#define NCHUNK 61          // 488 reps / 8; K = 976

DI u16 f2bf(float f) { union { __bf16 h; u16 s; } u; u.h = (__bf16)f; return u.s; }
DI float bf2f(u16 v) { union { u32 u; float f; } w; w.u = ((u32)v) << 16; return w.f; }

// ------------------------------------------------------------------
// prep kernel: ONE dispatch, no memset, no atomics.  One thread per
// packed-fragment u16: gathers its monomial's <=6 distinct U-index
// permutations, sums, converts to bf16, writes coalesced.
// Fragment layout (matches main's staging copy exactly):
// uint4 idx = chunk*64 + l; lane l: path = l&31, q = l>>5; u16 j in
// [0,8): feature slot = chunk*16 + q*8 + j.  Paths 28..31 are zero.
// ------------------------------------------------------------------
#define PREP_THREADS (NCHUNK * 64 * 8)     // 31232 u16 = 61 KB

__global__ void prep_kernel(const float* __restrict__ U3, const float* __restrict__ U2,
                            const float* __restrict__ U1, u16* __restrict__ Sfrag16) {
  const int tid = blockIdx.x * 256 + threadIdx.x;
  if (tid >= PREP_THREADS) return;
  const int j = tid & 7, l = (tid >> 3) & 63, chunk = tid >> 9;
  const int path = l & 31, q = l >> 5;
  const RepT m = g_T8.slotmono[chunk * 16 + q * 8 + j];
  float v = 0.f;
  if (m.t == 3 && path < 23) {
    const int a = m.a, b = m.b, d = m.c;
    v = U3[((a * 16 + b) * 16 + d) * 23 + path];
    if (a == b && b == d) {
      // single distinct permutation
    } else if (a == b) {            // (a,a,d): +ada, +daa
      v += U3[((a * 16 + d) * 16 + a) * 23 + path]
         + U3[((d * 16 + a) * 16 + a) * 23 + path];
    } else if (b == d) {            // (a,b,b): +bab, +bba
      v += U3[((b * 16 + a) * 16 + b) * 23 + path]
         + U3[((b * 16 + b) * 16 + a) * 23 + path];
    } else {                        // all distinct: 6 perms
      v += U3[((a * 16 + d) * 16 + b) * 23 + path]
         + U3[((b * 16 + a) * 16 + d) * 23 + path]
         + U3[((b * 16 + d) * 16 + a) * 23 + path]
         + U3[((d * 16 + a) * 16 + b) * 23 + path]
         + U3[((d * 16 + b) * 16 + a) * 23 + path];
    }
  } else if (m.t == 2 && path >= 23 && path < 27) {
    const int k = path - 23, a = m.a, b = m.b;
    v = U2[(a * 16 + b) * 4 + k];
    if (a != b) v += U2[(b * 16 + a) * 4 + k];
  } else if (m.t == 1 && path == 27) {
    v = U1[m.a];
  }
  Sfrag16[tid] = f2bf(v);
}

// ------------------------------------------------------------------
// main kernel (32x32x16 MFMA).  Journal of hard-won constraints:
//  - NEVER pass a min-waves launch_bounds arg that DEMANDS occupancy
//    beyond the VGPR budget (round 0: (1024,8) clamped to 32 VGPR ->
//    430 MB/dispatch scratch traffic).  (512,4) here RELAXES the
//    budget to 128 VGPR (LDS already caps us at 2 blocks/CU = 4
//    waves/EU) - safe direction.
//  - NO sched_barrier (prior round 10: 8x regression).
//  - w-reads block-coalesced once (prior round 5: 990 MB L2 fetch).
//  - Round 2 lesson: K-splitting doubles per-wave fixed costs and
//    occupancy does NOT respond to LDS sizing.  Round 3 goes the other
//    way: FEWER, DENSER waves.  32x32x16 tile = 32 pairs/wave, 1
//    ds_read + 1 MFMA per chunk -> LDS pipe halved (57->28 us), wave
//    count halved (prologue total halved), same FLOPs, full K per wave
//    (one-shot store, no atomics).
// ------------------------------------------------------------------
template<int R>
DI float featf(const float* xr) {
  constexpr RepT rp = TT8.rep[R];
  if constexpr (rp.t == 3) return xr[rp.a] * xr[rp.b] * xr[rp.c];
  else if constexpr (rp.t == 2) return xr[rp.a] * xr[rp.b];
  else if constexpr (rp.t == 1) return xr[rp.a];
  else return 0.f;
}

template<int C>
DI bf16x8 make_B(const float* xr) {
  bf16x8 r;
  r[0] = (__bf16)featf<C * 8 + 0>(xr);
  r[1] = (__bf16)featf<C * 8 + 1>(xr);
  r[2] = (__bf16)featf<C * 8 + 2>(xr);
  r[3] = (__bf16)featf<C * 8 + 3>(xr);
  r[4] = (__bf16)featf<C * 8 + 4>(xr);
  r[5] = (__bf16)featf<C * 8 + 5>(xr);
  r[6] = (__bf16)featf<C * 8 + 6>(xr);
  r[7] = (__bf16)featf<C * 8 + 7>(xr);
  return r;
}

// A: 32 paths x 16 K fragment from LDS (one ds_read_b128); B: 8
// features of this pair.  B built before the A-load to keep A's live
// range ds_read -> MFMA.
template<int C>
DI void chunk_step(const uint4* sfl, const float* xr, f32x16& acc) {
  const bf16x8 B = make_B<C>(xr);
  const bf16x8 A = *reinterpret_cast<const bf16x8*>(sfl + C * 64);
  acc = __builtin_amdgcn_mfma_f32_32x32x16_bf16(A, B, acc, 0, 0, 0);
}

template<int... Cs>
DI void run_chunks(std::integer_sequence<int, Cs...>, const uint4* sfl,
                   const float* xr, f32x16& acc) {
  (chunk_step<Cs>(sfl, xr, acc), ...);
}

// xr[v] = x[pair][(v + 8q) & 15] via float4-group rotation (2 groups = 8)
DI void load_xr(const float* __restrict__ x, int pair, int q, float* xr) {
  const float* base = x + pair * 16;
#pragma unroll
  for (int u = 0; u < 4; u++) {
    const int g = (u + 2 * q) & 3;
    const float4 v = *(const float4*)(base + g * 4);
    xr[u * 4 + 0] = v.x;
    xr[u * 4 + 1] = v.y;
    xr[u * 4 + 2] = v.z;
    xr[u * 4 + 3] = v.w;
  }
}

// 512-thread blocks: 8 waves = 2 nodes (4 waves x 32 pairs each).
// LDS = 61 KB sfrag (shared) + 2*8 KB wbl = 77 KB -> 2 blocks/CU.
// launch_bounds (512,4): 4 waves/EU is exactly the LDS-bound occupancy;
// grants a 128-VGPR budget (expected use ~60-90, no spill).
__global__ __launch_bounds__(512, 4) void main_kernel(
    const float* __restrict__ x, const float* __restrict__ y,
    const float* __restrict__ w3, const float* __restrict__ w2, const float* __restrict__ w1,
    const uint4* __restrict__ Sfrag, float* __restrict__ out)
{
  __shared__ uint4 sfrag[NCHUNK * 64];         // 62464 B: S in A-frag order
  __shared__ u16  wbl[2][32 * 128];            // 16384 B: WB[path][c] bf16, per node
  const int tid = threadIdx.x;
  const int node0 = blockIdx.x * 2;

  // stage S: straight uint4 copy (prep already packed bf16 fragments)
  for (int idx = tid; idx < NCHUNK * 64; idx += 512) sfrag[idx] = Sfrag[idx];

  // per-node WB = y[b] @ concat(w3,w2,w1).  256 threads/node:
  // tl = tid&255 -> p = tl>>3 (32 paths), c-16-seg = (tl&7)*16.
  // Rows 28..31: wsrc null -> zeros written (branchless epilogue).
  const int nl = tid >> 8;                     // node-local index 0/1
  const int bnode = node0 + nl;
  {
    const int tl = tid & 255;
    const int p  = tl >> 3;
    const int c0 = (tl & 7) * 16;
    float yv[EN];
#pragma unroll
    for (int e = 0; e < EN; e++) yv[e] = y[bnode * EN + e];
    float acc[16];
#pragma unroll
    for (int m = 0; m < 16; m++) acc[m] = 0.f;
    const float* wsrc = nullptr; int stride = 0;
    if (p < 23)       { wsrc = w3 + p * 128;        stride = 23 * 128; }
    else if (p < 27)  { wsrc = w2 + (p - 23) * 128; stride = 4 * 128; }
    else if (p == 27) { wsrc = w1;                  stride = 128; }
    if (wsrc) {
      for (int e = 0; e < EN; e++) {
        const float* src = wsrc + e * stride + c0;
        const float4 v0 = *(const float4*)(src);
        const float4 v1 = *(const float4*)(src + 4);
        const float4 v2 = *(const float4*)(src + 8);
        const float4 v3 = *(const float4*)(src + 12);
        acc[0]  += yv[e] * v0.x; acc[1]  += yv[e] * v0.y;
        acc[2]  += yv[e] * v0.z; acc[3]  += yv[e] * v0.w;
        acc[4]  += yv[e] * v1.x; acc[5]  += yv[e] * v1.y;
        acc[6]  += yv[e] * v1.z; acc[7]  += yv[e] * v1.w;
        acc[8]  += yv[e] * v2.x; acc[9]  += yv[e] * v2.y;
        acc[10] += yv[e] * v2.z; acc[11] += yv[e] * v2.w;
        acc[12] += yv[e] * v3.x; acc[13] += yv[e] * v3.y;
        acc[14] += yv[e] * v3.z; acc[15] += yv[e] * v3.w;
      }
    }
#pragma unroll
    for (int m = 0; m < 16; m++) wbl[nl][p * 128 + c0 + m] = f2bf(acc[m]);
  }
  __syncthreads();

  // wave handles 32 pairs; 4 waves per node, 2 nodes per block
  const int w = tid >> 6, wn = w & 3;
  const int lane = tid & 63, col = lane & 31, q = lane >> 5;
  const int pair0 = bnode * 128 + wn * 32 + col;

  float xr[16];
  load_xr(x, pair0, q, xr);

  const uint4* sfl = sfrag + lane;
  f32x16 acc = {0.f, 0.f, 0.f, 0.f, 0.f, 0.f, 0.f, 0.f,
                0.f, 0.f, 0.f, 0.f, 0.f, 0.f, 0.f, 0.f};
  run_chunks(std::make_integer_sequence<int, NCHUNK>{}, sfl, xr, acc);

  // epilogue: out[pair] = sum_p D[p][pair] * WB[p][c], reduce over the
  // two lane-halves.  D layout (32x32, m74/m101-verified):
  // col = lane&31 = pair, row = (reg&3) + 8*(reg>>2) + 4*q = path.
  // Rows 28..31 (q=1, reg 12..15) have zero D (zero A-rows) and zero
  // wbl -> branchless.
  const int cc = wn * 32 + col;              // channel = pair0 % 128
  float p0 = 0.f;
#pragma unroll
  for (int r = 0; r < 16; r++) {
    const int row = (r & 3) + 8 * (r >> 2) + 4 * q;
    p0 += acc[r] * bf2f(wbl[nl][row * 128 + cc]);
  }
  p0 += __shfl_xor(p0, 32);
  if (q == 0) out[pair0] = p0;
}

// ------------------------------------------------------------------
extern "C" void kernel_launch(void* const* d_in, const int* in_sizes, int n_in,
                              void* d_out, int out_size, void* d_ws, size_t ws_size,
                              hipStream_t stream) {
  const float* x  = (const float*)d_in[0];
  const float* y  = (const float*)d_in[1];
  const float* U3 = (const float*)d_in[2];
  const float* U2 = (const float*)d_in[3];
  const float* U1 = (const float*)d_in[4];
  const float* w3 = (const float*)d_in[5];
  const float* w2 = (const float*)d_in[6];
  const float* w1 = (const float*)d_in[7];
  u16*   Sfrag16 = (u16*)d_ws;
  float* out     = (float*)d_out;

  hipLaunchKernelGGL(prep_kernel, dim3(PREP_THREADS / 256), dim3(256), 0, stream,
                     U3, U2, U1, Sfrag16);
  hipLaunchKernelGGL(main_kernel, dim3(BN / 2), dim3(512), 0, stream,
                     x, y, w3, w2, w1, (const uint4*)d_ws, out);
}